// Round 1
// 278.864 us; speedup vs baseline: 1.0058x; 1.0058x over previous
//
#include <hip/hip_runtime.h>

// ---------------- problem constants ----------------
#define NN   10000     // nodes
#define E0   160000    // raw edges
#define ET   170000    // edges + self loops
#define DIN  165       // input channels
#define KP   192       // DIN padded to 32x for MFMA K-loop
#define HID  1024      // 8 heads * 128
#define NH   8
#define BP   200       // LDS row pitch for gemm1 B-tile (conflict-free, 16B-aligned rows)
#define K2P  1032      // LDS row pitch for gemm2 B

// dtypes (settled r6): ALL float tensors f32, edge_index int32, OUTPUT f32.

typedef __bf16 bf16x8 __attribute__((ext_vector_type(8)));
typedef float  f32x4  __attribute__((ext_vector_type(4)));
typedef float  f32x2  __attribute__((ext_vector_type(2)));

__device__ __forceinline__ float bf2f(unsigned short u) {
    unsigned int i = ((unsigned int)u) << 16;
    return __builtin_bit_cast(float, i);
}
__device__ __forceinline__ unsigned short f2bf(float f) {
    unsigned int i = __builtin_bit_cast(unsigned int, f);
    i += 0x7fffu + ((i >> 16) & 1u);   // round-to-nearest-even
    return (unsigned short)(i >> 16);
}
__device__ __forceinline__ float fin(float x) {
    return fminf(fmaxf(x, -1e30f), 1e30f);
}
__device__ __forceinline__ int clampi(int s) {
    return min(max(s, 0), NN - 1);
}
__device__ __forceinline__ void unpack8(uint4 u, float* f) {
    f[0]=bf2f((unsigned short)(u.x)); f[1]=bf2f((unsigned short)(u.x>>16));
    f[2]=bf2f((unsigned short)(u.y)); f[3]=bf2f((unsigned short)(u.y>>16));
    f[4]=bf2f((unsigned short)(u.z)); f[5]=bf2f((unsigned short)(u.z>>16));
    f[6]=bf2f((unsigned short)(u.w)); f[7]=bf2f((unsigned short)(u.w>>16));
}
// one packed u32 (2 bf16) -> f32x2 in 2 VALU ops (lshl / and)
__device__ __forceinline__ f32x2 up2(unsigned int u) {
    f32x2 r;
    r.x = __builtin_bit_cast(float, u << 16);
    r.y = __builtin_bit_cast(float, u & 0xffff0000u);
    return r;
}

// ---------------- debug ----------------
__global__ __launch_bounds__(256) void debug_fill(float* __restrict__ out, float val) {
    int i = blockIdx.x * 256 + threadIdx.x;
    if (i < NN) out[i] = val;
}

// ---------------- BN1: column stats over x [NN, DIN] f32 ----------------
__global__ __launch_bounds__(256) void bn1_stats(const float* __restrict__ x,
                                                 float* __restrict__ colsum, float* __restrict__ colsq) {
    int r0 = blockIdx.x * 125;
    int c = threadIdx.x;
    if (c >= DIN) return;
    float acc = 0.f, sq = 0.f;
    for (int r = r0; r < r0 + 125; ++r) {
        float v = x[(size_t)r * DIN + c];
        acc += v; sq += v * v;
    }
    atomicAdd(&colsum[c], acc);
    atomicAdd(&colsq[c], sq);
}

// normalized, K-padded hn [NN,KP] bf16; affine computed inline
__global__ __launch_bounds__(256) void bn1_apply(const float* __restrict__ x,
                                                 const float* __restrict__ colsum, const float* __restrict__ colsq,
                                                 const float* __restrict__ gamma, const float* __restrict__ beta,
                                                 unsigned short* __restrict__ hn) {
    int idx = blockIdx.x * 256 + threadIdx.x;   // NN*KP threads
    if (idx >= NN * KP) return;
    int r = idx / KP, c = idx - r * KP;
    float v = 0.f;
    if (c < DIN) {
        float mu  = colsum[c] * (1.f / NN);
        float var = fmaxf(colsq[c] * (1.f / NN) - mu * mu, 0.f);
        float a = gamma[c] * rsqrtf(var + 1e-5f);
        float b = beta[c] - mu * a;
        v = fin(x[(size_t)r * DIN + c] * a + b);
    }
    hn[idx] = f2bf(v);
}

// ---------------- W1 transpose (LDS-tiled, coalesced both sides) ----------------
__global__ __launch_bounds__(256) void w1_transpose(const float* __restrict__ wl,
                                                    const float* __restrict__ wr,
                                                    unsigned short* __restrict__ wlt,
                                                    unsigned short* __restrict__ wrt) {
    const float* src    = blockIdx.z ? wr  : wl;
    unsigned short* dst = blockIdx.z ? wrt : wlt;
    __shared__ float ts[32][65];
    const int k0 = blockIdx.x * 32;
    const int n0 = blockIdx.y * 64;
    const int tid = threadIdx.x;
    for (int idx = tid; idx < 32 * 64; idx += 256) {
        int k = idx >> 6, n = idx & 63;
        ts[k][n] = (k0 + k < DIN) ? src[(size_t)(k0 + k) * HID + n0 + n] : 0.f;
    }
    __syncthreads();
    for (int idx = tid; idx < 64 * 32; idx += 256) {
        int n = idx >> 5, k = idx & 31;
        dst[(size_t)(n0 + n) * KP + k0 + k] = f2bf(ts[k][n]);
    }
}

// ---------------- GEMM1 (MFMA, r15: L+R merged — one A-load feeds 16 MFMAs) ----------
// Both W-tiles staged (2 x 25.6KB LDS). Was: separate z-slices, each re-reading hn
// (MFMA:A-load 4:1, 2528 blocks, ~40us inferred). Now 8:1, 1264 blocks, hn traffic /2.
__global__ __launch_bounds__(256) void gemm1_kernel(
    const unsigned short* __restrict__ hn,
    const unsigned short* __restrict__ wlt,  // [HID][KP] bf16
    const unsigned short* __restrict__ wrt,
    const float* __restrict__ bl,
    const float* __restrict__ br,
    unsigned short* __restrict__ xl,
    unsigned short* __restrict__ xr) {
    __shared__ unsigned short bs[2][64 * BP];   // 51.2 KB (L, R)
    const int tid  = threadIdx.x;
    const int lane = tid & 63;
    const int wave = tid >> 6;
    const int col  = lane & 15;
    const int q    = lane >> 4;
    const int n0   = blockIdx.y * 64;

    // stage both B-tiles: coalesced uint2 reads, contiguous LDS writes
    for (int idx = tid; idx < 64 * 48 * 2; idx += 256) {
        int z = idx >= 64 * 48;
        int rem = z ? idx - 64 * 48 : idx;
        int r = rem / 48, c = rem - r * 48;
        const unsigned short* wt = z ? wrt : wlt;
        uint2 v = *(const uint2*)(wt + (size_t)(n0 + r) * KP + c * 4);
        *(uint2*)&bs[z][r * BP + c * 4] = v;
    }
    __syncthreads();

    const int mbase = blockIdx.x * 128 + wave * 32;
    const int am0 = mbase + col;
    const int am1 = am0 + 16;
    const bool aok0 = (am0 < NN), aok1 = (am1 < NN);

    f32x4 accL[2][4], accR[2][4];
    #pragma unroll
    for (int m = 0; m < 2; ++m)
        for (int nt = 0; nt < 4; ++nt)
            for (int r = 0; r < 4; ++r) { accL[m][nt][r] = 0.f; accR[m][nt][r] = 0.f; }

    #pragma unroll
    for (int kt = 0; kt < 6; ++kt) {
        const int kk = kt * 32 + q * 8;
        uint4 a0u = make_uint4(0u,0u,0u,0u), a1u = make_uint4(0u,0u,0u,0u);
        if (aok0) a0u = *(const uint4*)(hn + (size_t)am0 * KP + kk);
        if (aok1) a1u = *(const uint4*)(hn + (size_t)am1 * KP + kk);
        bf16x8 a0 = __builtin_bit_cast(bf16x8, a0u);
        bf16x8 a1 = __builtin_bit_cast(bf16x8, a1u);
        #pragma unroll
        for (int nt = 0; nt < 4; ++nt) {
            bf16x8 bfl = __builtin_bit_cast(bf16x8, *(const uint4*)&bs[0][(nt * 16 + col) * BP + kk]);
            accL[0][nt] = __builtin_amdgcn_mfma_f32_16x16x32_bf16(a0, bfl, accL[0][nt], 0, 0, 0);
            accL[1][nt] = __builtin_amdgcn_mfma_f32_16x16x32_bf16(a1, bfl, accL[1][nt], 0, 0, 0);
            bf16x8 bfr = __builtin_bit_cast(bf16x8, *(const uint4*)&bs[1][(nt * 16 + col) * BP + kk]);
            accR[0][nt] = __builtin_amdgcn_mfma_f32_16x16x32_bf16(a0, bfr, accR[0][nt], 0, 0, 0);
            accR[1][nt] = __builtin_amdgcn_mfma_f32_16x16x32_bf16(a1, bfr, accR[1][nt], 0, 0, 0);
        }
    }

    #pragma unroll
    for (int nt = 0; nt < 4; ++nt) {
        const int nc = n0 + nt * 16 + col;
        const float bLv = bl[nc];
        const float bRv = br[nc];
        #pragma unroll
        for (int m = 0; m < 2; ++m) {
            #pragma unroll
            for (int r = 0; r < 4; ++r) {
                const int row = mbase + m * 16 + q * 4 + r;
                if (row < NN) {
                    xl[(size_t)row * HID + nc] = f2bf(fin(accL[m][nt][r] + bLv));
                    xr[(size_t)row * HID + nc] = f2bf(fin(accR[m][nt][r] + bRv));
                }
            }
        }
    }
}

// ---------------- edge counting-sort by dst ----------------
__global__ __launch_bounds__(256) void edge_hist(const int* __restrict__ ei, int* __restrict__ deg) {
    int e = blockIdx.x * 256 + threadIdx.x;
    if (e >= ET) return;
    int d = (e < E0) ? ei[E0 + e] : (e - E0);
    atomicAdd(&deg[clampi(d)], 1);
}

// single-block scan + degree-descending node permutation
__global__ __launch_bounds__(1024) void scan_kernel(const int* __restrict__ deg,
                                                    int* __restrict__ offs, int* __restrict__ cur,
                                                    int* __restrict__ perm) {
    __shared__ int wsum[16];
    __shared__ int bins[64];
    __shared__ int bcur[64];
    const int tid = threadIdx.x;
    const int base = tid * 10;
    int loc[10];
    int run = 0;
    #pragma unroll
    for (int j = 0; j < 10; ++j) {
        int idx = base + j;
        int v = (idx < NN) ? deg[idx] : 0;
        loc[j] = run;
        run += v;
    }
    const int lane = tid & 63;
    const int w = tid >> 6;
    int inc = run;
    #pragma unroll
    for (int s = 1; s < 64; s <<= 1) {
        int t = __shfl_up(inc, s);
        if (lane >= s) inc += t;
    }
    if (lane == 63) wsum[w] = inc;
    if (tid < 64) bins[tid] = 0;
    __syncthreads();
    int woff = 0;
    #pragma unroll
    for (int k = 0; k < 16; ++k) woff += (k < w) ? wsum[k] : 0;
    const int toff = woff + inc - run;
    #pragma unroll
    for (int j = 0; j < 10; ++j) {
        int idx = base + j;
        if (idx < NN) {
            int e = toff + loc[j]; offs[idx] = e; cur[idx] = e;
            atomicAdd(&bins[63 - min(deg[idx], 63)], 1);   // descending-degree bucket
        }
    }
    if (tid == 1023) offs[NN] = woff + inc;
    __syncthreads();
    if (tid < 64) {   // wave 0: exclusive scan of 64 bins
        int v = bins[tid];
        int binc = v;
        #pragma unroll
        for (int s = 1; s < 64; s <<= 1) {
            int t = __shfl_up(binc, s);
            if (tid >= s) binc += t;
        }
        bcur[tid] = binc - v;
    }
    __syncthreads();
    #pragma unroll
    for (int j = 0; j < 10; ++j) {
        int idx = base + j;
        if (idx < NN) {
            int pos = atomicAdd(&bcur[63 - min(deg[idx], 63)], 1);
            perm[pos] = idx;
        }
    }
}

__global__ __launch_bounds__(256) void edge_scatter(const int* __restrict__ ei,
                                                    int* __restrict__ cur, int* __restrict__ ssrc) {
    int e = blockIdx.x * 256 + threadIdx.x;
    if (e >= ET) return;
    int s, d;
    if (e < E0) { s = ei[e]; d = ei[E0 + e]; }
    else        { s = e - E0; d = e - E0; }
    int pos = atomicAdd(&cur[clampi(d)], 1);
    if (pos >= 0 && pos < ET) ssrc[pos] = clampi(s);
}

// ---------------- GAT1 wave-per-node (degree-sorted order): -> agg bf16 ----
// r16: 2-edge-ahead software pipeline (prefetch next pair's rows during current
// pair's compute) + f32x2 channel math (packed v_pk_*_f32 eligible). Source rows
// kept packed in uint4 regs, unpacked on use (bounds VGPR with prefetch live).
// Alias (agg=xr1) safe by program order within the wave (same row i).
__global__ __launch_bounds__(256) void gat1_node(
    const unsigned short* __restrict__ xl1, const unsigned short* xr1,
    const float* __restrict__ att1, const float* __restrict__ bias1,
    const int* __restrict__ offs, const int* __restrict__ ssrc,
    const int* __restrict__ perm,
    unsigned short* agg) {
    const int lane = threadIdx.x & 63;
    const int wave = threadIdx.x >> 6;
    const int i = perm[blockIdx.x * 4 + wave];   // degree-descending: long nodes start first
    const int e0 = offs[i];
    const int e1 = max(offs[i + 1], e0 + 1);     // every node has >=1 edge (self-loop)

    f32x2 xr2[8], at2[8], o2[8];
    {
        const uint4* xp = (const uint4*)(xr1 + (size_t)i * HID + lane * 16);
        uint4 u0 = xp[0], u1 = xp[1];
        unsigned int w[8] = {u0.x, u0.y, u0.z, u0.w, u1.x, u1.y, u1.z, u1.w};
        const float4* ap = (const float4*)(att1 + lane * 16);
        float4 a0 = ap[0], a1 = ap[1], a2 = ap[2], a3 = ap[3];
        float af[16] = {a0.x,a0.y,a0.z,a0.w, a1.x,a1.y,a1.z,a1.w,
                        a2.x,a2.y,a2.z,a2.w, a3.x,a3.y,a3.z,a3.w};
        #pragma unroll
        for (int j = 0; j < 8; ++j) {
            xr2[j] = up2(w[j]);
            at2[j].x = af[2*j]; at2[j].y = af[2*j+1];
            o2[j].x = 0.f; o2[j].y = 0.f;
        }
    }
    float s = 0.f;

    // clamped edge-row loader (branch-free; e1-1 >= e0 always valid)
    auto lded = [&](int e, uint4& u0, uint4& u1) {
        int ee = min(e, e1 - 1);
        int sidx = clampi(ssrc[ee]);
        const uint4* xp = (const uint4*)(xl1 + (size_t)sidx * HID + lane * 16);
        u0 = xp[0]; u1 = xp[1];
    };
    // attention weight for one edge from packed regs (unpack-on-use)
    auto logit = [&](const uint4& u0, const uint4& u1) -> float {
        unsigned int w[8] = {u0.x, u0.y, u0.z, u0.w, u1.x, u1.y, u1.z, u1.w};
        f32x2 p = {0.f, 0.f}, q = {0.f, 0.f};
        #pragma unroll
        for (int j = 0; j < 8; j += 2) {
            f32x2 v0 = up2(w[j])     + xr2[j];
            f32x2 v1 = up2(w[j + 1]) + xr2[j + 1];
            p = __builtin_elementwise_fma(at2[j],     __builtin_elementwise_max(v0, 0.2f * v0), p);
            q = __builtin_elementwise_fma(at2[j + 1], __builtin_elementwise_max(v1, 0.2f * v1), q);
        }
        p += q;
        float r = p.x + p.y;
        r += __shfl_xor(r, 1); r += __shfl_xor(r, 2); r += __shfl_xor(r, 4);
        return __expf(fminf(r, 50.f));
    };
    auto accum = [&](const uint4& u0, const uint4& u1, float a) {
        unsigned int w[8] = {u0.x, u0.y, u0.z, u0.w, u1.x, u1.y, u1.z, u1.w};
        f32x2 av = {a, a};
        #pragma unroll
        for (int j = 0; j < 8; ++j)
            o2[j] = __builtin_elementwise_fma(av, up2(w[j]), o2[j]);
    };

    uint4 a0, a1, b0, b1, n0, n1, n2, n3;
    lded(e0,     a0, a1);
    lded(e0 + 1, b0, b1);
    int e = e0;
    while (e + 1 < e1) {
        lded(e + 2, n0, n1);     // prefetch next pair: in flight across this pair's compute
        lded(e + 3, n2, n3);
        float aa0 = logit(a0, a1);
        float aa1 = logit(b0, b1);
        s += aa0 + aa1;
        accum(a0, a1, aa0);
        accum(b0, b1, aa1);
        a0 = n0; a1 = n1; b0 = n2; b1 = n3;
        e += 2;
    }
    if (e < e1) {               // odd-degree tail: a-regs hold edge e1-1
        float aa = logit(a0, a1);
        s += aa;
        accum(a0, a1, aa);
    }

    const float inv = 1.f / (s + 1e-16f);
    const float4* bp = (const float4*)(bias1 + lane * 16);
    float4 bq0 = bp[0], bq1 = bp[1], bq2 = bp[2], bq3 = bp[3];
    float bb[16] = {bq0.x,bq0.y,bq0.z,bq0.w, bq1.x,bq1.y,bq1.z,bq1.w,
                    bq2.x,bq2.y,bq2.z,bq2.w, bq3.x,bq3.y,bq3.z,bq3.w};
    unsigned short ov[16];
    #pragma unroll
    for (int j = 0; j < 8; ++j) {
        ov[2*j]   = f2bf(fin(o2[j].x * inv + bb[2*j]));
        ov[2*j+1] = f2bf(fin(o2[j].y * inv + bb[2*j+1]));
    }
    uint4* op = (uint4*)(agg + (size_t)i * HID + lane * 16);
    op[0] = *(const uint4*)&ov[0];
    op[1] = *(const uint4*)&ov[8];
}

// ---------------- BN2 stats over agg [NN,HID] bf16 ----------------
__global__ __launch_bounds__(256) void bn2_stats(const unsigned short* __restrict__ agg,
                                                 float* __restrict__ colsum, float* __restrict__ colsq) {
    int r0 = blockIdx.x * 125;
    int t = threadIdx.x;
    float s0=0,s1=0,s2=0,s3=0,q0=0,q1=0,q2=0,q3=0;
    for (int r = r0; r < r0 + 125; ++r) {
        const ushort4 u = *(const ushort4*)(agg + (size_t)r * HID + t * 4);
        float v0=bf2f(u.x), v1=bf2f(u.y), v2=bf2f(u.z), v3=bf2f(u.w);
        s0+=v0; q0+=v0*v0; s1+=v1; q1+=v1*v1;
        s2+=v2; q2+=v2*v2; s3+=v3; q3+=v3*v3;
    }
    atomicAdd(&colsum[t*4+0], s0); atomicAdd(&colsq[t*4+0], q0);
    atomicAdd(&colsum[t*4+1], s1); atomicAdd(&colsq[t*4+1], q1);
    atomicAdd(&colsum[t*4+2], s2); atomicAdd(&colsq[t*4+2], q2);
    atomicAdd(&colsum[t*4+3], s3); atomicAdd(&colsq[t*4+3], q3);
}

// ---------------- GEMM2 (MFMA, BN2 affine + leaky fused into A-path) -----------
__global__ __launch_bounds__(256) void gemm2_kernel(
    const unsigned short* __restrict__ agg,
    const float* __restrict__ colsum, const float* __restrict__ colsq,
    const float* __restrict__ gamma, const float* __restrict__ beta,
    const float* __restrict__ wl2, const float* __restrict__ wr2,
    const float* __restrict__ bl2, const float* __restrict__ br2,
    float* __restrict__ xl2, float* __restrict__ xr2) {
    __shared__ unsigned short bs[16 * K2P];   // 33 KB
    __shared__ float a2s[HID], b2s[HID];      // 8 KB affine table
    const int tid  = threadIdx.x;
    const int lane = tid & 63;
    const int wave = tid >> 6;
    const int col  = lane & 15;
    const int q    = lane >> 4;

    for (int idx = tid; idx < 16 * HID; idx += 256) {
        int n = idx >> 10, k = idx & (HID - 1);
        float v = (n < 8) ? wl2[k * 8 + n] : wr2[k * 8 + (n - 8)];
        bs[n * K2P + k] = f2bf(v);
    }
    for (int c = tid; c < HID; c += 256) {
        float mu  = colsum[c] * (1.f / NN);
        float var = fmaxf(colsq[c] * (1.f / NN) - mu * mu, 0.f);
        float a = gamma[c] * rsqrtf(var + 1e-5f);
        a2s[c] = a; b2s[c] = beta[c] - mu * a;
    }
    __syncthreads();

    const int mtile = blockIdx.x * 4 + wave;
    if (mtile >= NN / 16) return;
    const int m0 = mtile * 16;
    const int am = m0 + col;

    f32x4 acc;
    acc[0] = acc[1] = acc[2] = acc[3] = 0.f;
    #pragma unroll
    for (int kt = 0; kt < 32; ++kt) {
        const int kk = kt * 32 + q * 8;
        uint4 u = *(const uint4*)(agg + (size_t)am * HID + kk);
        float xv[8];
        unpack8(u, xv);
        unsigned short hv[8];
        #pragma unroll
        for (int j = 0; j < 8; ++j) {
            float v = xv[j] * a2s[kk + j] + b2s[kk + j];
            v = fmaxf(v, 0.01f * v);          // leaky 0.01
            hv[j] = f2bf(fin(v));
        }
        bf16x8 af = __builtin_bit_cast(bf16x8, *(const uint4*)hv);
        bf16x8 bf = __builtin_bit_cast(bf16x8, *(const uint4*)&bs[col * K2P + kk]);
        acc = __builtin_amdgcn_mfma_f32_16x16x32_bf16(af, bf, acc, 0, 0, 0);
    }

    const float bv = (col < 8) ? bl2[col] : br2[col - 8];
    float* outp = (col < 8) ? (xl2 + col) : (xr2 + (col - 8));
    #pragma unroll
    for (int r = 0; r < 4; ++r) {
        const int row = m0 + q * 4 + r;
        outp[row * 8] = fin(acc[r] + bv);
    }
}

// ---------------- GAT2 single-pass (degree-sorted order) ----------------
__global__ __launch_bounds__(256) void gat2_node(
    const float* __restrict__ xl2, const float* __restrict__ xr2,
    const float* __restrict__ att2, const float* __restrict__ bias2,
    const int* __restrict__ offs, const int* __restrict__ ssrc,
    const int* __restrict__ perm,
    float* __restrict__ out) {
    const int lane = threadIdx.x & 63;
    const int wave = threadIdx.x >> 6;
    const int i = perm[blockIdx.x * 4 + wave];
    const int h = lane & 7, slot = lane >> 3;
    const int e0 = offs[i];
    const int e1 = max(offs[i + 1], e0);
    const float xr_h = xr2[i * 8 + h];
    const float att_h = att2[h];
    float ssum = 0.f, wsum = 0.f;
    for (int eb = e0; eb < e1; eb += 8) {
        int e = eb + slot;
        if (e < e1) {
            float xlv = xl2[clampi(ssrc[e]) * 8 + h];
            float v = xlv + xr_h;
            v = fmaxf(v, 0.2f * v);
            float a = __expf(fminf(fin(att_h * v), 50.f));
            ssum += a; wsum += a * xlv;
        }
    }
    ssum += __shfl_xor(ssum, 8); ssum += __shfl_xor(ssum, 16); ssum += __shfl_xor(ssum, 32);
    wsum += __shfl_xor(wsum, 8); wsum += __shfl_xor(wsum, 16); wsum += __shfl_xor(wsum, 32);
    float v = fin(wsum / (ssum + 1e-16f));
    v += __shfl_xor(v, 1); v += __shfl_xor(v, 2); v += __shfl_xor(v, 4);
    if (lane == 0) out[i] = fin(v * 0.125f + bias2[0]);
}

// ---------------- launch ----------------
extern "C" void kernel_launch(void* const* d_in, const int* in_sizes, int n_in,
                              void* d_out, int out_size, void* d_ws, size_t ws_size,
                              hipStream_t stream) {
    float* out = (float*)d_out;   // reference output dtype is float32

    static const int expected[18] = {
        NN * DIN, DIN, DIN, DIN * HID, HID, DIN * HID, HID, HID, HID,
        HID, HID, HID * NH, NH, HID * NH, NH, NH, 1, 2 * E0
    };
    if (n_in != 18) {
        debug_fill<<<(NN + 255) / 256, 256, 0, stream>>>(out, 8192.f + 64.f * (float)n_in);
        return;
    }
    for (int i = 0; i < 18; ++i) {
        if (in_sizes[i] != expected[i]) {
            debug_fill<<<(NN + 255) / 256, 256, 0, stream>>>(out, 4096.f + 32.f * (float)i);
            return;
        }
    }

    const float* x      = (const float*)d_in[0];
    const float* gamma1 = (const float*)d_in[1];
    const float* beta1  = (const float*)d_in[2];
    const float* Wl1    = (const float*)d_in[3];
    const float* bl1    = (const float*)d_in[4];
    const float* Wr1    = (const float*)d_in[5];
    const float* br1    = (const float*)d_in[6];
    const float* att1   = (const float*)d_in[7];
    const float* bias1  = (const float*)d_in[8];
    const float* gamma2 = (const float*)d_in[9];
    const float* beta2  = (const float*)d_in[10];
    const float* Wl2    = (const float*)d_in[11];
    const float* bl2    = (const float*)d_in[12];
    const float* Wr2    = (const float*)d_in[13];
    const float* br2    = (const float*)d_in[14];
    const float* att2   = (const float*)d_in[15];
    const float* bias2  = (const float*)d_in[16];
    const int*   ei     = (const int*)d_in[17];

    char* p = (char*)d_ws;
    auto alloc = [&](size_t bytes) -> void* {
        void* r = (void*)p;
        p += (bytes + 255) & ~(size_t)255;
        return r;
    };
    unsigned short* xl1  = (unsigned short*)alloc((size_t)NN * HID * 2);  // 20.48 MB
    unsigned short* xr1  = (unsigned short*)alloc((size_t)NN * HID * 2);  // 20.48 MB
    unsigned short* agg  = xr1;                                           // ALIAS (see gat1_node)
    unsigned short* hn   = (unsigned short*)alloc((size_t)NN * KP * 2);   // 3.84 MB
    unsigned short* wlt  = (unsigned short*)alloc((size_t)HID * KP * 2);  // 0.39 MB
    unsigned short* wrt  = (unsigned short*)alloc((size_t)HID * KP * 2);  // 0.39 MB
    float*          xl2  = (float*)alloc((size_t)NN * 8 * 4);
    float*          xr2  = (float*)alloc((size_t)NN * 8 * 4);
    int*            offs = (int*)alloc((NN + 1) * 4);
    int*            cur  = (int*)alloc(NN * 4);
    int*            ssrc = (int*)alloc(ET * 4);
    int*            perm = (int*)alloc(NN * 4);
    char* zbase = p;
    float* colsum1 = (float*)alloc(DIN * 4);
    float* colsq1  = (float*)alloc(DIN * 4);
    float* colsum2 = (float*)alloc(HID * 4);
    float* colsq2  = (float*)alloc(HID * 4);
    int*   deg     = (int*)alloc(NN * 4);
    size_t zlen = (size_t)(p - zbase);
    hipMemsetAsync(zbase, 0, zlen, stream);

    // 11 launches (r16: gat1 software-pipelined)
    bn1_stats<<<80, 256, 0, stream>>>(x, colsum1, colsq1);
    bn1_apply<<<(NN * KP + 255) / 256, 256, 0, stream>>>(x, colsum1, colsq1, gamma1, beta1, hn);
    w1_transpose<<<dim3(6, 16, 2), 256, 0, stream>>>(Wl1, Wr1, wlt, wrt);
    gemm1_kernel<<<dim3((NN + 127) / 128, HID / 64), 256, 0, stream>>>(hn, wlt, wrt, bl1, br1, xl1, xr1);
    edge_hist<<<(ET + 255) / 256, 256, 0, stream>>>(ei, deg);
    scan_kernel<<<1, 1024, 0, stream>>>(deg, offs, cur, perm);
    edge_scatter<<<(ET + 255) / 256, 256, 0, stream>>>(ei, cur, ssrc);
    gat1_node<<<NN / 4, 256, 0, stream>>>(xl1, xr1, att1, bias1, offs, ssrc, perm, agg);
    bn2_stats<<<80, 256, 0, stream>>>(agg, colsum2, colsq2);
    gemm2_kernel<<<(NN / 16 + 3) / 4, 256, 0, stream>>>(agg, colsum2, colsq2, gamma2, beta2,
                                                        Wl2, Wr2, bl2, br2, xl2, xr2);
    gat2_node<<<NN / 4, 256, 0, stream>>>(xl2, xr2, att2, bias2, offs, ssrc, perm, out);
}